// Round 9
// baseline (481.562 us; speedup 1.0000x reference)
//
#include <hip/hip_runtime.h>
#include <hip/hip_bf16.h>
#include <cstdint>

#define NODES 50000
#define EDGES 400000
#define FIN   988
#define KP0   992      // FIN padded to multiple of 32
#define FH    256
#define FC    47

typedef __attribute__((ext_vector_type(8))) short short8;
typedef __attribute__((ext_vector_type(4))) float f32x4;

__device__ __forceinline__ ushort f2bf(float x) {      // RNE f32 -> bf16
    union { float f; uint32_t u; } v; v.f = x;
    uint32_t r = v.u + 0x7FFF + ((v.u >> 16) & 1);
    return (ushort)(r >> 16);
}
__device__ __forceinline__ float bf2f(ushort u) {
    union { uint32_t u; float f; } v; v.u = ((uint32_t)u) << 16;
    return v.f;
}
__device__ __forceinline__ void g2l16(const void* g, void* l) {
    __builtin_amdgcn_global_load_lds((const __attribute__((address_space(1))) void*)g,
                                     (__attribute__((address_space(3))) void*)l, 16, 0, 0);
}

// ---------------- CSR build ----------------
__global__ void k_deg_count(const int* __restrict__ dst, int* __restrict__ deg, int nE) {
    int i = blockIdx.x * blockDim.x + threadIdx.x;
    if (i < nE) atomicAdd(&deg[dst[i]], 1);
}

__global__ __launch_bounds__(1024) void k_scan(const int* __restrict__ deg,
                                               int* __restrict__ rowptr,
                                               int* __restrict__ cursor, int n) {
    __shared__ int sums[1024];
    const int t = threadIdx.x;
    const int chunk = (n + 1023) / 1024;
    const int b = t * chunk;
    const int e = min(b + chunk, n);
    int s = 0;
    for (int i = b; i < e; ++i) s += deg[i];
    sums[t] = s;
    __syncthreads();
    for (int off = 1; off < 1024; off <<= 1) {
        int v = 0;
        if (t >= off) v = sums[t - off];
        __syncthreads();
        if (t >= off) sums[t] += v;
        __syncthreads();
    }
    int excl = (t == 0) ? 0 : sums[t - 1];
    for (int i = b; i < e; ++i) {
        int d = deg[i];
        rowptr[i] = excl;
        cursor[i] = excl;
        excl += d;
    }
    if (t == 1023) rowptr[n] = sums[1023];
}

__global__ void k_fill(const int* __restrict__ src, const int* __restrict__ dst,
                       int* __restrict__ cursor, int* __restrict__ eidx, int nE) {
    int i = blockIdx.x * blockDim.x + threadIdx.x;
    if (i < nE) {
        int d = dst[i];
        int p = atomicAdd(&cursor[d], 1);
        eidx[p] = src[i];
    }
}

// ---------------- x (f32) -> xbf (bf16, K 988->992, PRE-SWIZZLED) ----------------
// stored 16B slot ss within 32-elem chunk c of row r holds logical slot
// sl = ss ^ ((r>>1)&3)  (same key as Wt/hbuf; matches GEMM frag reads).
__global__ void k_cvtx(const float* __restrict__ x, ushort* __restrict__ xbf) {
    int gid = blockIdx.x * blockDim.x + threadIdx.x;
    if (gid >= NODES * (KP0 / 8)) return;
    const int r  = gid / (KP0 / 8);
    const int s8 = gid - r * (KP0 / 8);
    const int c  = s8 >> 2, ss = s8 & 3;
    const int sl = ss ^ ((r >> 1) & 3);
    const int kb = c * 32 + sl * 8;
    const float* p = x + (size_t)r * FIN + kb;
    short8 o;
    if (kb + 8 <= FIN) {
        f32x4 v0 = *(const f32x4*)(p);
        f32x4 v1 = *(const f32x4*)(p + 4);
#pragma unroll
        for (int i = 0; i < 4; ++i) {
            o[i] = (short)f2bf(v0[i]);
            o[4 + i] = (short)f2bf(v1[i]);
        }
    } else {
#pragma unroll
        for (int i = 0; i < 8; ++i) {
            float f = (kb + i < FIN) ? p[i] : 0.f;
            o[i] = (short)f2bf(f);
        }
    }
    *(short8*)&xbf[(size_t)r * KP0 + c * 32 + ss * 8] = o;
}

// ---------------- merged weight transpose+convert, PRE-SWIZZLED ----------------
#define W0E (512 * KP0)
#define W1E (512 * FH)
#define W2E (128 * FH)
__global__ void k_cvtw(const float* __restrict__ Ws0, const float* __restrict__ Wn0,
                       const float* __restrict__ Ws1, const float* __restrict__ Wn1,
                       const float* __restrict__ Ws2, const float* __restrict__ Wn2,
                       ushort* __restrict__ Wt0, ushort* __restrict__ Wt1,
                       ushort* __restrict__ Wt2) {
    int gid = blockIdx.x * blockDim.x + threadIdx.x;
    if (gid < W0E) {
        int n = gid / KP0, ks = gid - n * KP0;
        int kl = (ks & ~31) + ((((ks >> 3) & 3) ^ ((n >> 1) & 3)) << 3) + (ks & 7);
        float v = 0.f;
        if (kl < FIN) v = (n < FH) ? Ws0[(size_t)kl * FH + n] : Wn0[(size_t)kl * FH + (n - FH)];
        Wt0[gid] = f2bf(v);
    } else if (gid < W0E + W1E) {
        int g = gid - W0E;
        int n = g >> 8, ks = g & 255;
        int kl = (ks & ~31) + ((((ks >> 3) & 3) ^ ((n >> 1) & 3)) << 3) + (ks & 7);
        float v = (n < FH) ? Ws1[(size_t)kl * FH + n] : Wn1[(size_t)kl * FH + (n - FH)];
        Wt1[g] = f2bf(v);
    } else if (gid < W0E + W1E + W2E) {
        int g = gid - W0E - W1E;
        int n = g >> 8, ks = g & 255;
        int kl = (ks & ~31) + ((((ks >> 3) & 3) ^ ((n >> 1) & 3)) << 3) + (ks & 7);
        float v = 0.f;
        if (n < FC) v = Ws2[(size_t)kl * FC + n];
        else if (n >= 64 && n < 64 + FC) v = Wn2[(size_t)kl * FC + (n - 64)];
        Wt2[g] = f2bf(v);
    }
}

// ---------------- bf16 MFMA GEMM: gload_lds + 4-buffer 3-ahead pipeline ----------------
// C[M][ldc](bf16) = A[M][lda](bf16, pre-swz) @ Bt[N][Kpad]^T (pre-swz).
// 128x128 tile, BK=32, 4 waves, 4x4 16x16x32 frags/wave. Per lane per tile:
// 4 global_load_lds (2 A + 2 B). 4 LDS buffers, 3 tiles prefetched ahead ->
// steady-state wait vmcnt(8) (= "tile it resident, 2 newer tiles in flight"),
// ~750cy of lookahead vs ~900cy HBM latency; tails vmcnt(4)/vmcnt(0).
// stage(it+3) issues right after barrier-1: its target buf[(it+3)&3] ==
// buf[(it-1)&3] was freed at iteration it-1's barrier-2. LDS 64KB -> 2 blk/CU.
#define BMT 128
#define BKT 32
#define TBUF 4096   // ushorts per tile buffer (A or B): 128 rows x 32

__global__ __launch_bounds__(256, 4) void k_mm(const ushort* __restrict__ A,
                                               const ushort* __restrict__ Bt,
                                               ushort* __restrict__ C,
                                               const int M, const int lda,
                                               const int Kpad, const int ldc,
                                               const int nbx) {
    // bijective XCD-chunk swizzle (safe for nwg % 8 != 0)
    const int nwg = gridDim.x;
    const int bid = blockIdx.x;
    const int q = nwg >> 3, r = nwg & 7;
    const int xcd = bid & 7, ii = bid >> 3;
    const int swz = (xcd < r ? xcd * (q + 1) : r * (q + 1) + (xcd - r) * q) + ii;
    const int bm = (swz / nbx) * BMT;
    const int bn = (swz % nbx) * BMT;

    __shared__ ushort As[4 * TBUF];
    __shared__ ushort Bs[4 * TBUF];

    const int t = threadIdx.x;
    const int wid = t >> 6, lane = t & 63;
    const int wr = (wid >> 1) * 64, wc = (wid & 1) * 64;
    const int lr = lane & 15, g = lane >> 4;

    f32x4 acc[4][4] = {};

    // ---- staging descriptors: chunk c = j*4+wid (1KB each), row = c*16+(lane>>2) ----
    const ushort* asrc[2]; const ushort* bsrc[2]; int cdst[2];
#pragma unroll
    for (int j = 0; j < 2; ++j) {
        const int c = j * 4 + wid;
        const int row = c * 16 + (lane >> 2);
        const int arow = min(bm + row, M - 1);
        asrc[j] = A + (size_t)arow * lda + ((lane & 3) << 3);
        bsrc[j] = Bt + (size_t)(bn + row) * Kpad + ((lane & 3) << 3);
        cdst[j] = c * 512;   // ushort offset within a tile buffer
    }

    // ---- frag-read offsets (key (row>>1)&3, matches pre-swizzle) ----
    int roA[4], roB[4];
#pragma unroll
    for (int m = 0; m < 4; ++m) {
        const int row = wr + m * 16 + lr;
        roA[m] = row * 32 + ((g ^ ((row >> 1) & 3)) << 3);
    }
#pragma unroll
    for (int n = 0; n < 4; ++n) {
        const int col = wc + n * 16 + lr;
        roB[n] = col * 32 + ((g ^ ((col >> 1) & 3)) << 3);
    }

    auto stage = [&](int tile, int h) {
        const int k0 = tile * BKT;
#pragma unroll
        for (int j = 0; j < 2; ++j) g2l16(asrc[j] + k0, &As[h * TBUF + cdst[j]]);
#pragma unroll
        for (int j = 0; j < 2; ++j) g2l16(bsrc[j] + k0, &Bs[h * TBUF + cdst[j]]);
    };

    const int nt = Kpad / BKT;
    stage(0, 0);
    if (nt > 1) stage(1, 1);
    if (nt > 2) stage(2, 2);

    for (int it = 0; it < nt; ++it) {
        // barrier-1: tile `it` resident (vmcnt in-order; 4 loads/lane/tile)
        if (it + 2 < nt)      asm volatile("s_waitcnt vmcnt(8)" ::: "memory");
        else if (it + 1 < nt) asm volatile("s_waitcnt vmcnt(4)" ::: "memory");
        else                  asm volatile("s_waitcnt vmcnt(0)" ::: "memory");
        __builtin_amdgcn_s_barrier();

        // prefetch tile it+3 into buf freed at (it-1)'s barrier-2
        if (it + 3 < nt) stage(it + 3, (it + 3) & 3);

        const int h = it & 3;
        const ushort* Ab = &As[h * TBUF];
        const ushort* Bb = &Bs[h * TBUF];
        short8 af[4], bfr[4];
#pragma unroll
        for (int m = 0; m < 4; ++m) af[m] = *(const short8*)&Ab[roA[m]];
#pragma unroll
        for (int n = 0; n < 4; ++n) bfr[n] = *(const short8*)&Bb[roB[n]];

        asm volatile("s_waitcnt lgkmcnt(0)" ::: "memory");
        __builtin_amdgcn_sched_barrier(0);
        __builtin_amdgcn_s_barrier();   // barrier-2: all waves done reading buf[h]

#pragma unroll
        for (int m = 0; m < 4; ++m)
#pragma unroll
            for (int n = 0; n < 4; ++n)
                acc[m][n] = __builtin_amdgcn_mfma_f32_16x16x32_bf16(af[m], bfr[n], acc[m][n], 0, 0, 0);
    }

#pragma unroll
    for (int m = 0; m < 4; ++m) {
#pragma unroll
        for (int i = 0; i < 4; ++i) {
            const int row = bm + wr + m * 16 + g * 4 + i;
            if (row >= M) continue;
#pragma unroll
            for (int n = 0; n < 4; ++n) {
                const int col = bn + wc + n * 16 + lr;
                C[(size_t)row * ldc + col] = f2bf(acc[m][n][i]);
            }
        }
    }
}

// ---------------- fused gather-aggregate + combine, F=256 ----------------
// hbuf written PRE-SWIZZLED (slot ^ ((node>>1)&3)) for the next GEMM's A staging.
__global__ void k_gac256(const ushort* __restrict__ C, const int* __restrict__ rowptr,
                         const int* __restrict__ eidx, const float* __restrict__ bias,
                         ushort* __restrict__ hout) {
    int gid = blockIdx.x * blockDim.x + threadIdx.x;
    int node = gid >> 6;
    if (node >= NODES) return;
    const int l4 = (gid & 63) << 2;
    const int beg = rowptr[node];
    const int end = rowptr[node + 1];
    float a0 = 0.f, a1 = 0.f, a2 = 0.f, a3 = 0.f;
    int e = beg;
    for (; e + 1 < end; e += 2) {
        const int s0 = eidx[e], s1 = eidx[e + 1];
        const ushort4 v0 = *(const ushort4*)&C[(size_t)s0 * 512 + 256 + l4];
        const ushort4 v1 = *(const ushort4*)&C[(size_t)s1 * 512 + 256 + l4];
        a0 += bf2f(v0.x) + bf2f(v1.x);
        a1 += bf2f(v0.y) + bf2f(v1.y);
        a2 += bf2f(v0.z) + bf2f(v1.z);
        a3 += bf2f(v0.w) + bf2f(v1.w);
    }
    if (e < end) {
        const int s = eidx[e];
        const ushort4 v = *(const ushort4*)&C[(size_t)s * 512 + 256 + l4];
        a0 += bf2f(v.x); a1 += bf2f(v.y); a2 += bf2f(v.z); a3 += bf2f(v.w);
    }
    const float inv = 1.f / (float)max(end - beg, 1);
    const ushort4 hs = *(const ushort4*)&C[(size_t)node * 512 + l4];
    const f32x4 bv = *(const f32x4*)&bias[l4];
    ushort4 w;
    w.x = f2bf(fmaxf(bf2f(hs.x) + a0 * inv + bv[0], 0.f));
    w.y = f2bf(fmaxf(bf2f(hs.y) + a1 * inv + bv[1], 0.f));
    w.z = f2bf(fmaxf(bf2f(hs.z) + a2 * inv + bv[2], 0.f));
    w.w = f2bf(fmaxf(bf2f(hs.w) + a3 * inv + bv[3], 0.f));
    const int scol = (l4 & ~31) + ((((l4 >> 3) & 3) ^ ((node >> 1) & 3)) << 3) + (l4 & 7);
    *(ushort4*)&hout[(size_t)node * 256 + scol] = w;
}

// ---------------- final layer gather, F=47, C2 bf16 [50000][128] ----------------
__global__ void k_gac47(const ushort* __restrict__ C, const int* __restrict__ rowptr,
                        const int* __restrict__ eidx, const float* __restrict__ bias,
                        float* __restrict__ out) {
    int gid = blockIdx.x * blockDim.x + threadIdx.x;
    int node = gid >> 6;
    if (node >= NODES) return;
    const int l = gid & 63;
    if (l >= FC) return;
    const int beg = rowptr[node];
    const int end = rowptr[node + 1];
    float acc = 0.f;
    int e = beg;
    for (; e + 1 < end; e += 2) {
        const int s0 = eidx[e], s1 = eidx[e + 1];
        acc += bf2f(C[(size_t)s0 * 128 + 64 + l]) + bf2f(C[(size_t)s1 * 128 + 64 + l]);
    }
    if (e < end) acc += bf2f(C[(size_t)eidx[e] * 128 + 64 + l]);
    const float inv = 1.f / (float)max(end - beg, 1);
    out[(size_t)node * FC + l] = bf2f(C[(size_t)node * 128 + l]) + acc * inv + bias[l];
}

extern "C" void kernel_launch(void* const* d_in, const int* in_sizes, int n_in,
                              void* d_out, int out_size, void* d_ws, size_t ws_size,
                              hipStream_t stream) {
    const float* x       = (const float*)d_in[0];
    const int*   src     = (const int*)d_in[1];
    const int*   dst     = (const int*)d_in[2];
    const float* Wself0  = (const float*)d_in[3];
    const float* Wneigh0 = (const float*)d_in[4];
    const float* b0      = (const float*)d_in[5];
    const float* Wself1  = (const float*)d_in[6];
    const float* Wneigh1 = (const float*)d_in[7];
    const float* b1      = (const float*)d_in[8];
    const float* Wself2  = (const float*)d_in[9];
    const float* Wneigh2 = (const float*)d_in[10];
    const float* b2      = (const float*)d_in[11];
    float* out = (float*)d_out;

    char* w = (char*)d_ws;
    ushort* Cbuf = (ushort*)w;   w += (size_t)NODES * 512 * 2;   // 51.2 MB
    ushort* xbf  = (ushort*)w;   w += (size_t)NODES * KP0 * 2;   // 99.2 MB
    ushort* hbuf = xbf;          // aliases xbf: xbf dead once L0 GEMM completes
    ushort* Wt0  = (ushort*)w;   w += (size_t)W0E * 2;
    ushort* Wt1  = (ushort*)w;   w += (size_t)W1E * 2;
    ushort* Wt2  = (ushort*)w;   w += (size_t)W2E * 2;
    int* rowptr  = (int*)w;      w += (NODES + 1) * sizeof(int);
    int* cursor  = (int*)w;      w += NODES * sizeof(int);
    int* eidx    = (int*)w;

    dim3 blk(256);

    // ---- CSR build ----
    hipMemsetAsync(cursor, 0, NODES * sizeof(int), stream);
    k_deg_count<<<(EDGES + 255) / 256, blk, 0, stream>>>(dst, cursor, EDGES);
    k_scan<<<1, 1024, 0, stream>>>(cursor, rowptr, cursor, NODES);
    k_fill<<<(EDGES + 255) / 256, blk, 0, stream>>>(src, dst, cursor, eidx, EDGES);

    // ---- conversions (pre-swizzled) ----
    k_cvtw<<<(W0E + W1E + W2E + 255) / 256, blk, 0, stream>>>(
        Wself0, Wneigh0, Wself1, Wneigh1, Wself2, Wneigh2, Wt0, Wt1, Wt2);
    k_cvtx<<<(NODES * (KP0 / 8) + 255) / 256, blk, 0, stream>>>(x, xbf);

    const int gat_blocks = (int)(((size_t)NODES * 64 + 255) / 256);
    const int nbyM = (NODES + BMT - 1) / BMT;   // 391

    // ---- Layer 0: C0 = xbf @ [Wself0|Wneigh0]  (M=50000, N=512, K=992) ----
    k_mm<<<dim3(4 * nbyM), blk, 0, stream>>>(xbf, Wt0, Cbuf, NODES, KP0, KP0, 512, 4);
    k_gac256<<<gat_blocks, blk, 0, stream>>>(Cbuf, rowptr, eidx, b0, hbuf);

    // ---- Layer 1: C1 = h1 @ [Wself1|Wneigh1]  (K=256) ----
    k_mm<<<dim3(4 * nbyM), blk, 0, stream>>>(hbuf, Wt1, Cbuf, NODES, FH, FH, 512, 4);
    k_gac256<<<gat_blocks, blk, 0, stream>>>(Cbuf, rowptr, eidx, b1, hbuf);

    // ---- Layer 2: C2 = h2 @ [Wself2|Wneigh2 padded]  (N=128, K=256) ----
    k_mm<<<dim3(nbyM), blk, 0, stream>>>(hbuf, Wt2, Cbuf, NODES, FH, FH, 128, 1);
    k_gac47<<<gat_blocks, blk, 0, stream>>>(Cbuf, rowptr, eidx, b2, out);
}

// Round 10
// 477.702 us; speedup vs baseline: 1.0081x; 1.0081x over previous
//
#include <hip/hip_runtime.h>
#include <hip/hip_bf16.h>
#include <cstdint>

#define NODES 50000
#define EDGES 400000
#define FIN   988
#define KP0   992      // FIN padded to multiple of 32
#define FH    256
#define FC    47

typedef __attribute__((ext_vector_type(8))) short short8;
typedef __attribute__((ext_vector_type(4))) float f32x4;

__device__ __forceinline__ ushort f2bf(float x) {      // RNE f32 -> bf16
    union { float f; uint32_t u; } v; v.f = x;
    uint32_t r = v.u + 0x7FFF + ((v.u >> 16) & 1);
    return (ushort)(r >> 16);
}
__device__ __forceinline__ float bf2f(ushort u) {
    union { uint32_t u; float f; } v; v.u = ((uint32_t)u) << 16;
    return v.f;
}
__device__ __forceinline__ void g2l16(const void* g, void* l) {
    __builtin_amdgcn_global_load_lds((const __attribute__((address_space(1))) void*)g,
                                     (__attribute__((address_space(3))) void*)l, 16, 0, 0);
}

// ---------------- CSR build ----------------
__global__ void k_deg_count(const int* __restrict__ dst, int* __restrict__ deg, int nE) {
    int i = blockIdx.x * blockDim.x + threadIdx.x;
    if (i < nE) atomicAdd(&deg[dst[i]], 1);
}

__global__ __launch_bounds__(1024) void k_scan(const int* __restrict__ deg,
                                               int* __restrict__ rowptr,
                                               int* __restrict__ cursor, int n) {
    __shared__ int sums[1024];
    const int t = threadIdx.x;
    const int chunk = (n + 1023) / 1024;
    const int b = t * chunk;
    const int e = min(b + chunk, n);
    int s = 0;
    for (int i = b; i < e; ++i) s += deg[i];
    sums[t] = s;
    __syncthreads();
    for (int off = 1; off < 1024; off <<= 1) {
        int v = 0;
        if (t >= off) v = sums[t - off];
        __syncthreads();
        if (t >= off) sums[t] += v;
        __syncthreads();
    }
    int excl = (t == 0) ? 0 : sums[t - 1];
    for (int i = b; i < e; ++i) {
        int d = deg[i];
        rowptr[i] = excl;
        cursor[i] = excl;
        excl += d;
    }
    if (t == 1023) rowptr[n] = sums[1023];
}

__global__ void k_fill(const int* __restrict__ src, const int* __restrict__ dst,
                       int* __restrict__ cursor, int* __restrict__ eidx, int nE) {
    int i = blockIdx.x * blockDim.x + threadIdx.x;
    if (i < nE) {
        int d = dst[i];
        int p = atomicAdd(&cursor[d], 1);
        eidx[p] = src[i];
    }
}

// ---------------- x (f32) -> xbf (bf16, K 988->992, PRE-SWIZZLED) ----------------
__global__ void k_cvtx(const float* __restrict__ x, ushort* __restrict__ xbf) {
    int gid = blockIdx.x * blockDim.x + threadIdx.x;
    if (gid >= NODES * (KP0 / 8)) return;
    const int r  = gid / (KP0 / 8);
    const int s8 = gid - r * (KP0 / 8);
    const int c  = s8 >> 2, ss = s8 & 3;
    const int sl = ss ^ ((r >> 1) & 3);
    const int kb = c * 32 + sl * 8;
    const float* p = x + (size_t)r * FIN + kb;
    short8 o;
    if (kb + 8 <= FIN) {
        f32x4 v0 = *(const f32x4*)(p);
        f32x4 v1 = *(const f32x4*)(p + 4);
#pragma unroll
        for (int i = 0; i < 4; ++i) {
            o[i] = (short)f2bf(v0[i]);
            o[4 + i] = (short)f2bf(v1[i]);
        }
    } else {
#pragma unroll
        for (int i = 0; i < 8; ++i) {
            float f = (kb + i < FIN) ? p[i] : 0.f;
            o[i] = (short)f2bf(f);
        }
    }
    *(short8*)&xbf[(size_t)r * KP0 + c * 32 + ss * 8] = o;
}

// ---------------- merged weight transpose+convert, PRE-SWIZZLED, coalesced reads ----------------
// n-fastest mapping: consecutive threads read consecutive n of W[k][n] (coalesced);
// the strided bf16 writes are absorbed by the store path. Stored slot of logical
// k-index kl within its 32-chunk is (kl>>3&3)^((n>>1)&3) (involution, matches GEMM reads).
#define W0E (512 * KP0)
#define W1E (512 * FH)
#define W2E (128 * FH)
__global__ void k_cvtw(const float* __restrict__ Ws0, const float* __restrict__ Wn0,
                       const float* __restrict__ Ws1, const float* __restrict__ Wn1,
                       const float* __restrict__ Ws2, const float* __restrict__ Wn2,
                       ushort* __restrict__ Wt0, ushort* __restrict__ Wt1,
                       ushort* __restrict__ Wt2) {
    int gid = blockIdx.x * blockDim.x + threadIdx.x;
    if (gid < W0E) {
        int kl = gid >> 9, n = gid & 511;
        int ks = (kl & ~31) | ((((kl >> 3) & 3) ^ ((n >> 1) & 3)) << 3) | (kl & 7);
        float v = 0.f;
        if (kl < FIN) v = (n < FH) ? Ws0[(size_t)kl * FH + n] : Wn0[(size_t)kl * FH + (n - FH)];
        Wt0[(size_t)n * KP0 + ks] = f2bf(v);
    } else if (gid < W0E + W1E) {
        int gg = gid - W0E;
        int k = gg >> 9, n = gg & 511;
        int ks = (k & ~31) | ((((k >> 3) & 3) ^ ((n >> 1) & 3)) << 3) | (k & 7);
        float v = (n < FH) ? Ws1[(size_t)k * FH + n] : Wn1[(size_t)k * FH + (n - FH)];
        Wt1[(size_t)n * FH + ks] = f2bf(v);
    } else if (gid < W0E + W1E + W2E) {
        int gg = gid - W0E - W1E;
        int k = gg >> 7, n = gg & 127;
        int ks = (k & ~31) | ((((k >> 3) & 3) ^ ((n >> 1) & 3)) << 3) | (k & 7);
        float v = 0.f;
        if (n < FC) v = Ws2[(size_t)k * FC + n];
        else if (n >= 64 && n < 64 + FC) v = Wn2[(size_t)k * FC + (n - 64)];
        Wt2[(size_t)n * FH + ks] = f2bf(v);
    }
}

// ---------------- bf16 MFMA GEMM: gload_lds + 5-buffer, ONE barrier/K-step ----------------
// C[M][ldc](bf16) = A[M][lda](bf16, pre-swz) @ Bt[N][Kpad]^T (pre-swz).
// 128x128 tile, BK=32, 4 waves, 4x4 16x16x32 frags/wave, 4 gload_lds/lane/tile.
// 5 rotating LDS buffers, 4 tiles prefetched ahead; counted waits
// vmcnt(12/8/4/0) = "tile it resident" (vmcnt is in-order, m135).
// ONE s_barrier per iter: with >=4 buffers, stage(it+4) targets the buffer
// read at it-1, and any wave past barrier(it) already consumed its it-1 frags
// (register dep before barrier arrival) -> no second barrier, no lgkm drain.
// ds_read->MFMA scheduling left to the compiler (fine-grained lgkmcnt, m97).
// sched_barrier(0) after the barrier pins ds_reads below it (cross-wave DMA).
#define BMT 128
#define BKT 32
#define TBUF 4096   // ushorts per tile buffer: 128 rows x 32
#define NBUF 5

__global__ __launch_bounds__(256, 4) void k_mm(const ushort* __restrict__ A,
                                               const ushort* __restrict__ Bt,
                                               ushort* __restrict__ C,
                                               const int M, const int lda,
                                               const int Kpad, const int ldc,
                                               const int nbx) {
    // bijective XCD-chunk swizzle (safe for nwg % 8 != 0)
    const int nwg = gridDim.x;
    const int bid = blockIdx.x;
    const int q = nwg >> 3, r = nwg & 7;
    const int xcd = bid & 7, ii = bid >> 3;
    const int swz = (xcd < r ? xcd * (q + 1) : r * (q + 1) + (xcd - r) * q) + ii;
    const int bm = (swz / nbx) * BMT;
    const int bn = (swz % nbx) * BMT;

    __shared__ ushort As[NBUF * TBUF];
    __shared__ ushort Bs[NBUF * TBUF];

    const int t = threadIdx.x;
    const int wid = t >> 6, lane = t & 63;
    const int wr = (wid >> 1) * 64, wc = (wid & 1) * 64;
    const int lr = lane & 15, g = lane >> 4;

    f32x4 acc[4][4] = {};

    // staging descriptors: chunk c = j*4+wid (1KB each), row = c*16+(lane>>2)
    const ushort* asrc[2]; const ushort* bsrc[2]; int cdst[2];
#pragma unroll
    for (int j = 0; j < 2; ++j) {
        const int c = j * 4 + wid;
        const int row = c * 16 + (lane >> 2);
        const int arow = min(bm + row, M - 1);
        asrc[j] = A + (size_t)arow * lda + ((lane & 3) << 3);
        bsrc[j] = Bt + (size_t)(bn + row) * Kpad + ((lane & 3) << 3);
        cdst[j] = c * 512;
    }

    // frag-read offsets (key (row>>1)&3, matches pre-swizzle; measured 0 conflicts)
    int roA[4], roB[4];
#pragma unroll
    for (int m = 0; m < 4; ++m) {
        const int row = wr + m * 16 + lr;
        roA[m] = row * 32 + ((g ^ ((row >> 1) & 3)) << 3);
    }
#pragma unroll
    for (int n = 0; n < 4; ++n) {
        const int col = wc + n * 16 + lr;
        roB[n] = col * 32 + ((g ^ ((col >> 1) & 3)) << 3);
    }

    auto stage = [&](int tile) {
        const int k0 = tile * BKT;
        const int ho = (tile % NBUF) * TBUF;
        g2l16(asrc[0] + k0, &As[ho + cdst[0]]);
        g2l16(asrc[1] + k0, &As[ho + cdst[1]]);
        g2l16(bsrc[0] + k0, &Bs[ho + cdst[0]]);
        g2l16(bsrc[1] + k0, &Bs[ho + cdst[1]]);
    };

    const int nt = Kpad / BKT;
#pragma unroll
    for (int p = 0; p < 4; ++p) if (p < nt) stage(p);

    for (int it = 0; it < nt; ++it) {
        const int rmn = nt - 1 - it;
        if (rmn >= 3)      asm volatile("s_waitcnt vmcnt(12)" ::: "memory");
        else if (rmn == 2) asm volatile("s_waitcnt vmcnt(8)"  ::: "memory");
        else if (rmn == 1) asm volatile("s_waitcnt vmcnt(4)"  ::: "memory");
        else               asm volatile("s_waitcnt vmcnt(0)"  ::: "memory");
        __builtin_amdgcn_s_barrier();           // all waves: tile `it` resident
        __builtin_amdgcn_sched_barrier(0);      // pin ds_reads below the barrier

        if (it + 4 < nt) stage(it + 4);         // target buf was freed at it-1

        const ushort* Ab = &As[(it % NBUF) * TBUF];
        const ushort* Bb = &Bs[(it % NBUF) * TBUF];
        short8 af[4], bfr[4];
#pragma unroll
        for (int m = 0; m < 4; ++m) af[m] = *(const short8*)&Ab[roA[m]];
#pragma unroll
        for (int n = 0; n < 4; ++n) bfr[n] = *(const short8*)&Bb[roB[n]];
#pragma unroll
        for (int m = 0; m < 4; ++m)
#pragma unroll
            for (int n = 0; n < 4; ++n)
                acc[m][n] = __builtin_amdgcn_mfma_f32_16x16x32_bf16(af[m], bfr[n], acc[m][n], 0, 0, 0);
    }

#pragma unroll
    for (int m = 0; m < 4; ++m) {
#pragma unroll
        for (int i = 0; i < 4; ++i) {
            const int row = bm + wr + m * 16 + g * 4 + i;
            if (row >= M) continue;
#pragma unroll
            for (int n = 0; n < 4; ++n) {
                const int col = bn + wc + n * 16 + lr;
                C[(size_t)row * ldc + col] = f2bf(acc[m][n][i]);
            }
        }
    }
}

// ---------------- fused gather-aggregate + combine, F=256 ----------------
// hbuf written PRE-SWIZZLED (slot ^ ((node>>1)&3)) for the next GEMM's A staging.
__global__ void k_gac256(const ushort* __restrict__ C, const int* __restrict__ rowptr,
                         const int* __restrict__ eidx, const float* __restrict__ bias,
                         ushort* __restrict__ hout) {
    int gid = blockIdx.x * blockDim.x + threadIdx.x;
    int node = gid >> 6;
    if (node >= NODES) return;
    const int l4 = (gid & 63) << 2;
    const int beg = rowptr[node];
    const int end = rowptr[node + 1];
    float a0 = 0.f, a1 = 0.f, a2 = 0.f, a3 = 0.f;
    int e = beg;
    for (; e + 1 < end; e += 2) {
        const int s0 = eidx[e], s1 = eidx[e + 1];
        const ushort4 v0 = *(const ushort4*)&C[(size_t)s0 * 512 + 256 + l4];
        const ushort4 v1 = *(const ushort4*)&C[(size_t)s1 * 512 + 256 + l4];
        a0 += bf2f(v0.x) + bf2f(v1.x);
        a1 += bf2f(v0.y) + bf2f(v1.y);
        a2 += bf2f(v0.z) + bf2f(v1.z);
        a3 += bf2f(v0.w) + bf2f(v1.w);
    }
    if (e < end) {
        const int s = eidx[e];
        const ushort4 v = *(const ushort4*)&C[(size_t)s * 512 + 256 + l4];
        a0 += bf2f(v.x); a1 += bf2f(v.y); a2 += bf2f(v.z); a3 += bf2f(v.w);
    }
    const float inv = 1.f / (float)max(end - beg, 1);
    const ushort4 hs = *(const ushort4*)&C[(size_t)node * 512 + l4];
    const f32x4 bv = *(const f32x4*)&bias[l4];
    ushort4 w;
    w.x = f2bf(fmaxf(bf2f(hs.x) + a0 * inv + bv[0], 0.f));
    w.y = f2bf(fmaxf(bf2f(hs.y) + a1 * inv + bv[1], 0.f));
    w.z = f2bf(fmaxf(bf2f(hs.z) + a2 * inv + bv[2], 0.f));
    w.w = f2bf(fmaxf(bf2f(hs.w) + a3 * inv + bv[3], 0.f));
    const int scol = (l4 & ~31) + ((((l4 >> 3) & 3) ^ ((node >> 1) & 3)) << 3) + (l4 & 7);
    *(ushort4*)&hout[(size_t)node * 256 + scol] = w;
}

// ---------------- final layer gather, F=47, C2 bf16 [50000][128] ----------------
__global__ void k_gac47(const ushort* __restrict__ C, const int* __restrict__ rowptr,
                        const int* __restrict__ eidx, const float* __restrict__ bias,
                        float* __restrict__ out) {
    int gid = blockIdx.x * blockDim.x + threadIdx.x;
    int node = gid >> 6;
    if (node >= NODES) return;
    const int l = gid & 63;
    if (l >= FC) return;
    const int beg = rowptr[node];
    const int end = rowptr[node + 1];
    float acc = 0.f;
    int e = beg;
    for (; e + 1 < end; e += 2) {
        const int s0 = eidx[e], s1 = eidx[e + 1];
        acc += bf2f(C[(size_t)s0 * 128 + 64 + l]) + bf2f(C[(size_t)s1 * 128 + 64 + l]);
    }
    if (e < end) acc += bf2f(C[(size_t)eidx[e] * 128 + 64 + l]);
    const float inv = 1.f / (float)max(end - beg, 1);
    out[(size_t)node * FC + l] = bf2f(C[(size_t)node * 128 + l]) + acc * inv + bias[l];
}

extern "C" void kernel_launch(void* const* d_in, const int* in_sizes, int n_in,
                              void* d_out, int out_size, void* d_ws, size_t ws_size,
                              hipStream_t stream) {
    const float* x       = (const float*)d_in[0];
    const int*   src     = (const int*)d_in[1];
    const int*   dst     = (const int*)d_in[2];
    const float* Wself0  = (const float*)d_in[3];
    const float* Wneigh0 = (const float*)d_in[4];
    const float* b0      = (const float*)d_in[5];
    const float* Wself1  = (const float*)d_in[6];
    const float* Wneigh1 = (const float*)d_in[7];
    const float* b1      = (const float*)d_in[8];
    const float* Wself2  = (const float*)d_in[9];
    const float* Wneigh2 = (const float*)d_in[10];
    const float* b2      = (const float*)d_in[11];
    float* out = (float*)d_out;

    char* w = (char*)d_ws;
    ushort* Cbuf = (ushort*)w;   w += (size_t)NODES * 512 * 2;   // 51.2 MB
    ushort* xbf  = (ushort*)w;   w += (size_t)NODES * KP0 * 2;   // 99.2 MB
    ushort* hbuf = xbf;          // aliases xbf: xbf dead once L0 GEMM completes
    ushort* Wt0  = (ushort*)w;   w += (size_t)W0E * 2;
    ushort* Wt1  = (ushort*)w;   w += (size_t)W1E * 2;
    ushort* Wt2  = (ushort*)w;   w += (size_t)W2E * 2;
    int* rowptr  = (int*)w;      w += (NODES + 1) * sizeof(int);
    int* cursor  = (int*)w;      w += NODES * sizeof(int);
    int* eidx    = (int*)w;

    dim3 blk(256);

    // ---- CSR build ----
    hipMemsetAsync(cursor, 0, NODES * sizeof(int), stream);
    k_deg_count<<<(EDGES + 255) / 256, blk, 0, stream>>>(dst, cursor, EDGES);
    k_scan<<<1, 1024, 0, stream>>>(cursor, rowptr, cursor, NODES);
    k_fill<<<(EDGES + 255) / 256, blk, 0, stream>>>(src, dst, cursor, eidx, EDGES);

    // ---- conversions (pre-swizzled) ----
    k_cvtw<<<(W0E + W1E + W2E + 255) / 256, blk, 0, stream>>>(
        Wself0, Wneigh0, Wself1, Wneigh1, Wself2, Wneigh2, Wt0, Wt1, Wt2);
    k_cvtx<<<(NODES * (KP0 / 8) + 255) / 256, blk, 0, stream>>>(x, xbf);

    const int gat_blocks = (int)(((size_t)NODES * 64 + 255) / 256);
    const int nbyM = (NODES + BMT - 1) / BMT;   // 391

    // ---- Layer 0: C0 = xbf @ [Wself0|Wneigh0]  (M=50000, N=512, K=992) ----
    k_mm<<<dim3(4 * nbyM), blk, 0, stream>>>(xbf, Wt0, Cbuf, NODES, KP0, KP0, 512, 4);
    k_gac256<<<gat_blocks, blk, 0, stream>>>(Cbuf, rowptr, eidx, b0, hbuf);

    // ---- Layer 1: C1 = h1 @ [Wself1|Wneigh1]  (K=256) ----
    k_mm<<<dim3(4 * nbyM), blk, 0, stream>>>(hbuf, Wt1, Cbuf, NODES, FH, FH, 512, 4);
    k_gac256<<<gat_blocks, blk, 0, stream>>>(Cbuf, rowptr, eidx, b1, hbuf);

    // ---- Layer 2: C2 = h2 @ [Wself2|Wneigh2 padded]  (N=128, K=256) ----
    k_mm<<<dim3(nbyM), blk, 0, stream>>>(hbuf, Wt2, Cbuf, NODES, FH, FH, 128, 1);
    k_gac47<<<gat_blocks, blk, 0, stream>>>(Cbuf, rowptr, eidx, b2, out);
}

// Round 11
// 475.652 us; speedup vs baseline: 1.0124x; 1.0043x over previous
//
#include <hip/hip_runtime.h>
#include <hip/hip_bf16.h>
#include <cstdint>

#define NODES 50000
#define EDGES 400000
#define FIN   988
#define KP0   992      // FIN padded to multiple of 32
#define FH    256
#define FC    47

typedef __attribute__((ext_vector_type(8))) short short8;
typedef __attribute__((ext_vector_type(4))) float f32x4;

__device__ __forceinline__ ushort f2bf(float x) {      // RNE f32 -> bf16
    union { float f; uint32_t u; } v; v.f = x;
    uint32_t r = v.u + 0x7FFF + ((v.u >> 16) & 1);
    return (ushort)(r >> 16);
}
__device__ __forceinline__ float bf2f(ushort u) {
    union { uint32_t u; float f; } v; v.u = ((uint32_t)u) << 16;
    return v.f;
}
__device__ __forceinline__ void g2l16(const void* g, void* l) {
    __builtin_amdgcn_global_load_lds((const __attribute__((address_space(1))) void*)g,
                                     (__attribute__((address_space(3))) void*)l, 16, 0, 0);
}

// ---------------- CSR build ----------------
__global__ void k_deg_count(const int* __restrict__ dst, int* __restrict__ deg, int nE) {
    int i = blockIdx.x * blockDim.x + threadIdx.x;
    if (i < nE) atomicAdd(&deg[dst[i]], 1);
}

__global__ __launch_bounds__(1024) void k_scan(const int* __restrict__ deg,
                                               int* __restrict__ rowptr,
                                               int* __restrict__ cursor, int n) {
    __shared__ int sums[1024];
    const int t = threadIdx.x;
    const int chunk = (n + 1023) / 1024;
    const int b = t * chunk;
    const int e = min(b + chunk, n);
    int s = 0;
    for (int i = b; i < e; ++i) s += deg[i];
    sums[t] = s;
    __syncthreads();
    for (int off = 1; off < 1024; off <<= 1) {
        int v = 0;
        if (t >= off) v = sums[t - off];
        __syncthreads();
        if (t >= off) sums[t] += v;
        __syncthreads();
    }
    int excl = (t == 0) ? 0 : sums[t - 1];
    for (int i = b; i < e; ++i) {
        int d = deg[i];
        rowptr[i] = excl;
        cursor[i] = excl;
        excl += d;
    }
    if (t == 1023) rowptr[n] = sums[1023];
}

__global__ void k_fill(const int* __restrict__ src, const int* __restrict__ dst,
                       int* __restrict__ cursor, int* __restrict__ eidx, int nE) {
    int i = blockIdx.x * blockDim.x + threadIdx.x;
    if (i < nE) {
        int d = dst[i];
        int p = atomicAdd(&cursor[d], 1);
        eidx[p] = src[i];
    }
}

// ---------------- x (f32) -> xbf (bf16, K 988->992, PRE-SWIZZLED) ----------------
__global__ void k_cvtx(const float* __restrict__ x, ushort* __restrict__ xbf) {
    int gid = blockIdx.x * blockDim.x + threadIdx.x;
    if (gid >= NODES * (KP0 / 8)) return;
    const int r  = gid / (KP0 / 8);
    const int s8 = gid - r * (KP0 / 8);
    const int c  = s8 >> 2, ss = s8 & 3;
    const int sl = ss ^ ((r >> 1) & 3);
    const int kb = c * 32 + sl * 8;
    const float* p = x + (size_t)r * FIN + kb;
    short8 o;
    if (kb + 8 <= FIN) {
        f32x4 v0 = *(const f32x4*)(p);
        f32x4 v1 = *(const f32x4*)(p + 4);
#pragma unroll
        for (int i = 0; i < 4; ++i) {
            o[i] = (short)f2bf(v0[i]);
            o[4 + i] = (short)f2bf(v1[i]);
        }
    } else {
#pragma unroll
        for (int i = 0; i < 8; ++i) {
            float f = (kb + i < FIN) ? p[i] : 0.f;
            o[i] = (short)f2bf(f);
        }
    }
    *(short8*)&xbf[(size_t)r * KP0 + c * 32 + ss * 8] = o;
}

// ---------------- merged weight transpose+convert, PRE-SWIZZLED, coalesced reads ----------------
#define W0E (512 * KP0)
#define W1E (512 * FH)
#define W2E (128 * FH)
__global__ void k_cvtw(const float* __restrict__ Ws0, const float* __restrict__ Wn0,
                       const float* __restrict__ Ws1, const float* __restrict__ Wn1,
                       const float* __restrict__ Ws2, const float* __restrict__ Wn2,
                       ushort* __restrict__ Wt0, ushort* __restrict__ Wt1,
                       ushort* __restrict__ Wt2) {
    int gid = blockIdx.x * blockDim.x + threadIdx.x;
    if (gid < W0E) {
        int kl = gid >> 9, n = gid & 511;
        int ks = (kl & ~31) | ((((kl >> 3) & 3) ^ ((n >> 1) & 3)) << 3) | (kl & 7);
        float v = 0.f;
        if (kl < FIN) v = (n < FH) ? Ws0[(size_t)kl * FH + n] : Wn0[(size_t)kl * FH + (n - FH)];
        Wt0[(size_t)n * KP0 + ks] = f2bf(v);
    } else if (gid < W0E + W1E) {
        int gg = gid - W0E;
        int k = gg >> 9, n = gg & 511;
        int ks = (k & ~31) | ((((k >> 3) & 3) ^ ((n >> 1) & 3)) << 3) | (k & 7);
        float v = (n < FH) ? Ws1[(size_t)k * FH + n] : Wn1[(size_t)k * FH + (n - FH)];
        Wt1[(size_t)n * FH + ks] = f2bf(v);
    } else if (gid < W0E + W1E + W2E) {
        int gg = gid - W0E - W1E;
        int k = gg >> 7, n = gg & 127;
        int ks = (k & ~31) | ((((k >> 3) & 3) ^ ((n >> 1) & 3)) << 3) | (k & 7);
        float v = 0.f;
        if (n < FC) v = Ws2[(size_t)k * FC + n];
        else if (n >= 64 && n < 64 + FC) v = Wn2[(size_t)k * FC + (n - 64)];
        Wt2[(size_t)n * FH + ks] = f2bf(v);
    }
}

// ================= 256x256 MFMA GEMM: gload_lds + 4-buffer 3-ahead, 1 barrier =================
// C[M][ldc](bf16) = A[M][lda](bf16, pre-swz) @ Bt[N][Kpad]^T (pre-swz).
// 512 threads = 8 waves (2 Mx4 N), per-wave output 128x64 = acc[8][4].
// Per K-step (BK=32): 256 MFMA (~1240cy) vs 128KB LDS traffic (~640cy) ->
// compute-dominant (the 128^2 tile was LDS-bound at 48KB/64 MFMA).
// Staging identical to the proven 128^2 skeleton: 4 gload_lds/lane/tile,
// 4 rotating 32KB buffers, 3 tiles ahead, counted vmcnt(8/4/0), ONE barrier
// (stage(it+3) targets the buffer consumed at it-1; any wave past barrier(it)
// already consumed its it-1 frags via the MFMA reg dependency).
#define TB2 8192    // ushorts per 256x32 tile buffer
#define NB2 4

__global__ __launch_bounds__(512, 2) void k_mm256(const ushort* __restrict__ A,
                                                  const ushort* __restrict__ Bt,
                                                  ushort* __restrict__ C,
                                                  const int M, const int lda,
                                                  const int Kpad, const int ldc,
                                                  const int nbx) {
    const int nwg = gridDim.x;
    const int bid = blockIdx.x;
    const int q = nwg >> 3, r = nwg & 7;
    const int xcd = bid & 7, ii = bid >> 3;
    const int swz = (xcd < r ? xcd * (q + 1) : r * (q + 1) + (xcd - r) * q) + ii;
    const int bm = (swz / nbx) * 256;
    const int bn = (swz % nbx) * 256;

    __shared__ ushort As[NB2 * TB2];   // 64 KB
    __shared__ ushort Bs[NB2 * TB2];   // 64 KB

    const int t = threadIdx.x;
    const int wid = t >> 6, lane = t & 63;
    const int wr = (wid >> 2) * 128, wc = (wid & 3) * 64;
    const int lr = lane & 15, g = lane >> 4;

    f32x4 acc[8][4] = {};

    // staging: 16 chunks of 1KB per 16KB tile; c = j*8+wid; row = c*16+(lane>>2)
    const ushort* asrc[2]; const ushort* bsrc[2]; int cdst[2];
#pragma unroll
    for (int j = 0; j < 2; ++j) {
        const int c = j * 8 + wid;
        const int row = c * 16 + (lane >> 2);
        const int arow = min(bm + row, M - 1);
        asrc[j] = A + (size_t)arow * lda + ((lane & 3) << 3);
        bsrc[j] = Bt + (size_t)(bn + row) * Kpad + ((lane & 3) << 3);
        cdst[j] = c * 512;
    }

    // frag-read offsets (swizzle key (row>>1)&3; measured 0 conflicts)
    int roA[8], roB[4];
#pragma unroll
    for (int m = 0; m < 8; ++m) {
        const int row = wr + m * 16 + lr;
        roA[m] = row * 32 + ((g ^ ((row >> 1) & 3)) << 3);
    }
#pragma unroll
    for (int n = 0; n < 4; ++n) {
        const int col = wc + n * 16 + lr;
        roB[n] = col * 32 + ((g ^ ((col >> 1) & 3)) << 3);
    }

    auto stage = [&](int tile) {
        const int k0 = tile * 32;
        const int ho = (tile & (NB2 - 1)) * TB2;
        g2l16(asrc[0] + k0, &As[ho + cdst[0]]);
        g2l16(asrc[1] + k0, &As[ho + cdst[1]]);
        g2l16(bsrc[0] + k0, &Bs[ho + cdst[0]]);
        g2l16(bsrc[1] + k0, &Bs[ho + cdst[1]]);
    };

    const int nt = Kpad / 32;
#pragma unroll
    for (int p = 0; p < 3; ++p) if (p < nt) stage(p);

    for (int it = 0; it < nt; ++it) {
        const int rmn = nt - 1 - it;
        if (rmn >= 2)      asm volatile("s_waitcnt vmcnt(8)" ::: "memory");
        else if (rmn == 1) asm volatile("s_waitcnt vmcnt(4)" ::: "memory");
        else               asm volatile("s_waitcnt vmcnt(0)" ::: "memory");
        __builtin_amdgcn_s_barrier();           // all waves: tile `it` resident
        __builtin_amdgcn_sched_barrier(0);      // pin ds_reads below the barrier

        if (it + 3 < nt) stage(it + 3);         // buf freed at it-1

        const ushort* Ab = &As[(it & (NB2 - 1)) * TB2];
        const ushort* Bb = &Bs[(it & (NB2 - 1)) * TB2];
        short8 af[8], bfr[4];
#pragma unroll
        for (int m = 0; m < 8; ++m) af[m] = *(const short8*)&Ab[roA[m]];
#pragma unroll
        for (int n = 0; n < 4; ++n) bfr[n] = *(const short8*)&Bb[roB[n]];
#pragma unroll
        for (int m = 0; m < 8; ++m)
#pragma unroll
            for (int n = 0; n < 4; ++n)
                acc[m][n] = __builtin_amdgcn_mfma_f32_16x16x32_bf16(af[m], bfr[n], acc[m][n], 0, 0, 0);
    }

#pragma unroll
    for (int m = 0; m < 8; ++m) {
#pragma unroll
        for (int i = 0; i < 4; ++i) {
            const int row = bm + wr + m * 16 + g * 4 + i;
            if (row >= M) continue;
#pragma unroll
            for (int n = 0; n < 4; ++n) {
                const int col = bn + wc + n * 16 + lr;
                C[(size_t)row * ldc + col] = f2bf(acc[m][n][i]);
            }
        }
    }
}

// ================= 128x128 MFMA GEMM (R10 structure) — used for L2 (N=128) =================
#define BMT 128
#define TBUF 4096
#define NBUF 5

__global__ __launch_bounds__(256, 4) void k_mm(const ushort* __restrict__ A,
                                               const ushort* __restrict__ Bt,
                                               ushort* __restrict__ C,
                                               const int M, const int lda,
                                               const int Kpad, const int ldc,
                                               const int nbx) {
    const int nwg = gridDim.x;
    const int bid = blockIdx.x;
    const int q = nwg >> 3, r = nwg & 7;
    const int xcd = bid & 7, ii = bid >> 3;
    const int swz = (xcd < r ? xcd * (q + 1) : r * (q + 1) + (xcd - r) * q) + ii;
    const int bm = (swz / nbx) * BMT;
    const int bn = (swz % nbx) * BMT;

    __shared__ ushort As[NBUF * TBUF];
    __shared__ ushort Bs[NBUF * TBUF];

    const int t = threadIdx.x;
    const int wid = t >> 6, lane = t & 63;
    const int wr = (wid >> 1) * 64, wc = (wid & 1) * 64;
    const int lr = lane & 15, g = lane >> 4;

    f32x4 acc[4][4] = {};

    const ushort* asrc[2]; const ushort* bsrc[2]; int cdst[2];
#pragma unroll
    for (int j = 0; j < 2; ++j) {
        const int c = j * 4 + wid;
        const int row = c * 16 + (lane >> 2);
        const int arow = min(bm + row, M - 1);
        asrc[j] = A + (size_t)arow * lda + ((lane & 3) << 3);
        bsrc[j] = Bt + (size_t)(bn + row) * Kpad + ((lane & 3) << 3);
        cdst[j] = c * 512;
    }

    int roA[4], roB[4];
#pragma unroll
    for (int m = 0; m < 4; ++m) {
        const int row = wr + m * 16 + lr;
        roA[m] = row * 32 + ((g ^ ((row >> 1) & 3)) << 3);
    }
#pragma unroll
    for (int n = 0; n < 4; ++n) {
        const int col = wc + n * 16 + lr;
        roB[n] = col * 32 + ((g ^ ((col >> 1) & 3)) << 3);
    }

    auto stage = [&](int tile) {
        const int k0 = tile * 32;
        const int ho = (tile % NBUF) * TBUF;
        g2l16(asrc[0] + k0, &As[ho + cdst[0]]);
        g2l16(asrc[1] + k0, &As[ho + cdst[1]]);
        g2l16(bsrc[0] + k0, &Bs[ho + cdst[0]]);
        g2l16(bsrc[1] + k0, &Bs[ho + cdst[1]]);
    };

    const int nt = Kpad / 32;
#pragma unroll
    for (int p = 0; p < 4; ++p) if (p < nt) stage(p);

    for (int it = 0; it < nt; ++it) {
        const int rmn = nt - 1 - it;
        if (rmn >= 3)      asm volatile("s_waitcnt vmcnt(12)" ::: "memory");
        else if (rmn == 2) asm volatile("s_waitcnt vmcnt(8)"  ::: "memory");
        else if (rmn == 1) asm volatile("s_waitcnt vmcnt(4)"  ::: "memory");
        else               asm volatile("s_waitcnt vmcnt(0)"  ::: "memory");
        __builtin_amdgcn_s_barrier();
        __builtin_amdgcn_sched_barrier(0);

        if (it + 4 < nt) stage(it + 4);

        const ushort* Ab = &As[(it % NBUF) * TBUF];
        const ushort* Bb = &Bs[(it % NBUF) * TBUF];
        short8 af[4], bfr[4];
#pragma unroll
        for (int m = 0; m < 4; ++m) af[m] = *(const short8*)&Ab[roA[m]];
#pragma unroll
        for (int n = 0; n < 4; ++n) bfr[n] = *(const short8*)&Bb[roB[n]];
#pragma unroll
        for (int m = 0; m < 4; ++m)
#pragma unroll
            for (int n = 0; n < 4; ++n)
                acc[m][n] = __builtin_amdgcn_mfma_f32_16x16x32_bf16(af[m], bfr[n], acc[m][n], 0, 0, 0);
    }

#pragma unroll
    for (int m = 0; m < 4; ++m) {
#pragma unroll
        for (int i = 0; i < 4; ++i) {
            const int row = bm + wr + m * 16 + g * 4 + i;
            if (row >= M) continue;
#pragma unroll
            for (int n = 0; n < 4; ++n) {
                const int col = bn + wc + n * 16 + lr;
                C[(size_t)row * ldc + col] = f2bf(acc[m][n][i]);
            }
        }
    }
}

// ---------------- fused gather-aggregate + combine, F=256 ----------------
__global__ void k_gac256(const ushort* __restrict__ C, const int* __restrict__ rowptr,
                         const int* __restrict__ eidx, const float* __restrict__ bias,
                         ushort* __restrict__ hout) {
    int gid = blockIdx.x * blockDim.x + threadIdx.x;
    int node = gid >> 6;
    if (node >= NODES) return;
    const int l4 = (gid & 63) << 2;
    const int beg = rowptr[node];
    const int end = rowptr[node + 1];
    float a0 = 0.f, a1 = 0.f, a2 = 0.f, a3 = 0.f;
    int e = beg;
    for (; e + 1 < end; e += 2) {
        const int s0 = eidx[e], s1 = eidx[e + 1];
        const ushort4 v0 = *(const ushort4*)&C[(size_t)s0 * 512 + 256 + l4];
        const ushort4 v1 = *(const ushort4*)&C[(size_t)s1 * 512 + 256 + l4];
        a0 += bf2f(v0.x) + bf2f(v1.x);
        a1 += bf2f(v0.y) + bf2f(v1.y);
        a2 += bf2f(v0.z) + bf2f(v1.z);
        a3 += bf2f(v0.w) + bf2f(v1.w);
    }
    if (e < end) {
        const int s = eidx[e];
        const ushort4 v = *(const ushort4*)&C[(size_t)s * 512 + 256 + l4];
        a0 += bf2f(v.x); a1 += bf2f(v.y); a2 += bf2f(v.z); a3 += bf2f(v.w);
    }
    const float inv = 1.f / (float)max(end - beg, 1);
    const ushort4 hs = *(const ushort4*)&C[(size_t)node * 512 + l4];
    const f32x4 bv = *(const f32x4*)&bias[l4];
    ushort4 w;
    w.x = f2bf(fmaxf(bf2f(hs.x) + a0 * inv + bv[0], 0.f));
    w.y = f2bf(fmaxf(bf2f(hs.y) + a1 * inv + bv[1], 0.f));
    w.z = f2bf(fmaxf(bf2f(hs.z) + a2 * inv + bv[2], 0.f));
    w.w = f2bf(fmaxf(bf2f(hs.w) + a3 * inv + bv[3], 0.f));
    const int scol = (l4 & ~31) + ((((l4 >> 3) & 3) ^ ((node >> 1) & 3)) << 3) + (l4 & 7);
    *(ushort4*)&hout[(size_t)node * 256 + scol] = w;
}

// ---------------- final layer gather, F=47, C2 bf16 [50000][128] ----------------
__global__ void k_gac47(const ushort* __restrict__ C, const int* __restrict__ rowptr,
                        const int* __restrict__ eidx, const float* __restrict__ bias,
                        float* __restrict__ out) {
    int gid = blockIdx.x * blockDim.x + threadIdx.x;
    int node = gid >> 6;
    if (node >= NODES) return;
    const int l = gid & 63;
    if (l >= FC) return;
    const int beg = rowptr[node];
    const int end = rowptr[node + 1];
    float acc = 0.f;
    int e = beg;
    for (; e + 1 < end; e += 2) {
        const int s0 = eidx[e], s1 = eidx[e + 1];
        acc += bf2f(C[(size_t)s0 * 128 + 64 + l]) + bf2f(C[(size_t)s1 * 128 + 64 + l]);
    }
    if (e < end) acc += bf2f(C[(size_t)eidx[e] * 128 + 64 + l]);
    const float inv = 1.f / (float)max(end - beg, 1);
    out[(size_t)node * FC + l] = bf2f(C[(size_t)node * 128 + l]) + acc * inv + bias[l];
}

extern "C" void kernel_launch(void* const* d_in, const int* in_sizes, int n_in,
                              void* d_out, int out_size, void* d_ws, size_t ws_size,
                              hipStream_t stream) {
    const float* x       = (const float*)d_in[0];
    const int*   src     = (const int*)d_in[1];
    const int*   dst     = (const int*)d_in[2];
    const float* Wself0  = (const float*)d_in[3];
    const float* Wneigh0 = (const float*)d_in[4];
    const float* b0      = (const float*)d_in[5];
    const float* Wself1  = (const float*)d_in[6];
    const float* Wneigh1 = (const float*)d_in[7];
    const float* b1      = (const float*)d_in[8];
    const float* Wself2  = (const float*)d_in[9];
    const float* Wneigh2 = (const float*)d_in[10];
    const float* b2      = (const float*)d_in[11];
    float* out = (float*)d_out;

    char* w = (char*)d_ws;
    ushort* Cbuf = (ushort*)w;   w += (size_t)NODES * 512 * 2;   // 51.2 MB
    ushort* xbf  = (ushort*)w;   w += (size_t)NODES * KP0 * 2;   // 99.2 MB
    ushort* hbuf = xbf;          // aliases xbf: xbf dead once L0 GEMM completes
    ushort* Wt0  = (ushort*)w;   w += (size_t)W0E * 2;
    ushort* Wt1  = (ushort*)w;   w += (size_t)W1E * 2;
    ushort* Wt2  = (ushort*)w;   w += (size_t)W2E * 2;
    int* rowptr  = (int*)w;      w += (NODES + 1) * sizeof(int);
    int* cursor  = (int*)w;      w += NODES * sizeof(int);
    int* eidx    = (int*)w;

    dim3 blk(256);

    // ---- CSR build ----
    hipMemsetAsync(cursor, 0, NODES * sizeof(int), stream);
    k_deg_count<<<(EDGES + 255) / 256, blk, 0, stream>>>(dst, cursor, EDGES);
    k_scan<<<1, 1024, 0, stream>>>(cursor, rowptr, cursor, NODES);
    k_fill<<<(EDGES + 255) / 256, blk, 0, stream>>>(src, dst, cursor, eidx, EDGES);

    // ---- conversions (pre-swizzled) ----
    k_cvtw<<<(W0E + W1E + W2E + 255) / 256, blk, 0, stream>>>(
        Wself0, Wneigh0, Wself1, Wneigh1, Wself2, Wneigh2, Wt0, Wt1, Wt2);
    k_cvtx<<<(NODES * (KP0 / 8) + 255) / 256, blk, 0, stream>>>(x, xbf);

    const int gat_blocks = (int)(((size_t)NODES * 64 + 255) / 256);
    const int nbyM2 = (NODES + 255) / 256;      // 196 (256-row tiles)
    const int nbyM  = (NODES + BMT - 1) / BMT;  // 391 (128-row tiles)

    // ---- Layer 0: C0 = xbf @ [Wself0|Wneigh0]  (M=50000, N=512, K=992) ----
    k_mm256<<<dim3(2 * nbyM2), dim3(512), 0, stream>>>(xbf, Wt0, Cbuf, NODES, KP0, KP0, 512, 2);
    k_gac256<<<gat_blocks, blk, 0, stream>>>(Cbuf, rowptr, eidx, b0, hbuf);

    // ---- Layer 1: C1 = h1 @ [Wself1|Wneigh1]  (K=256) ----
    k_mm256<<<dim3(2 * nbyM2), dim3(512), 0, stream>>>(hbuf, Wt1, Cbuf, NODES, FH, FH, 512, 2);
    k_gac256<<<gat_blocks, blk, 0, stream>>>(Cbuf, rowptr, eidx, b1, hbuf);

    // ---- Layer 2: C2 = h2 @ [Wself2|Wneigh2 padded]  (N=128, K=256) ----
    k_mm<<<dim3(nbyM), blk, 0, stream>>>(hbuf, Wt2, Cbuf, NODES, FH, FH, 128, 1);
    k_gac47<<<gat_blocks, blk, 0, stream>>>(Cbuf, rowptr, eidx, b2, out);
}

// Round 12
// 459.615 us; speedup vs baseline: 1.0478x; 1.0349x over previous
//
#include <hip/hip_runtime.h>
#include <hip/hip_bf16.h>
#include <cstdint>

#define NODES 50000
#define EDGES 400000
#define FIN   988
#define KP0   992      // FIN padded to multiple of 32
#define FH    256
#define FC    47

typedef __attribute__((ext_vector_type(8))) short short8;
typedef __attribute__((ext_vector_type(4))) float f32x4;

__device__ __forceinline__ ushort f2bf(float x) {      // RNE f32 -> bf16
    union { float f; uint32_t u; } v; v.f = x;
    uint32_t r = v.u + 0x7FFF + ((v.u >> 16) & 1);
    return (ushort)(r >> 16);
}
__device__ __forceinline__ float bf2f(ushort u) {
    union { uint32_t u; float f; } v; v.u = ((uint32_t)u) << 16;
    return v.f;
}
__device__ __forceinline__ void g2l16(const void* g, void* l) {
    __builtin_amdgcn_global_load_lds((const __attribute__((address_space(1))) void*)g,
                                     (__attribute__((address_space(3))) void*)l, 16, 0, 0);
}

// ---------------- CSR build ----------------
__global__ void k_deg_count(const int* __restrict__ dst, int* __restrict__ deg, int nE) {
    int i = blockIdx.x * blockDim.x + threadIdx.x;
    if (i < nE) atomicAdd(&deg[dst[i]], 1);
}

__global__ __launch_bounds__(1024) void k_scan(const int* __restrict__ deg,
                                               int* __restrict__ rowptr,
                                               int* __restrict__ cursor, int n) {
    __shared__ int sums[1024];
    const int t = threadIdx.x;
    const int chunk = (n + 1023) / 1024;
    const int b = t * chunk;
    const int e = min(b + chunk, n);
    int s = 0;
    for (int i = b; i < e; ++i) s += deg[i];
    sums[t] = s;
    __syncthreads();
    for (int off = 1; off < 1024; off <<= 1) {
        int v = 0;
        if (t >= off) v = sums[t - off];
        __syncthreads();
        if (t >= off) sums[t] += v;
        __syncthreads();
    }
    int excl = (t == 0) ? 0 : sums[t - 1];
    for (int i = b; i < e; ++i) {
        int d = deg[i];
        rowptr[i] = excl;
        cursor[i] = excl;
        excl += d;
    }
    if (t == 1023) rowptr[n] = sums[1023];
}

__global__ void k_fill(const int* __restrict__ src, const int* __restrict__ dst,
                       int* __restrict__ cursor, int* __restrict__ eidx, int nE) {
    int i = blockIdx.x * blockDim.x + threadIdx.x;
    if (i < nE) {
        int d = dst[i];
        int p = atomicAdd(&cursor[d], 1);
        eidx[p] = src[i];
    }
}

// ---------------- x (f32) -> xbf (bf16, K 988->992, PRE-SWIZZLED) ----------------
__global__ void k_cvtx(const float* __restrict__ x, ushort* __restrict__ xbf) {
    int gid = blockIdx.x * blockDim.x + threadIdx.x;
    if (gid >= NODES * (KP0 / 8)) return;
    const int r  = gid / (KP0 / 8);
    const int s8 = gid - r * (KP0 / 8);
    const int c  = s8 >> 2, ss = s8 & 3;
    const int sl = ss ^ ((r >> 1) & 3);
    const int kb = c * 32 + sl * 8;
    const float* p = x + (size_t)r * FIN + kb;
    short8 o;
    if (kb + 8 <= FIN) {
        f32x4 v0 = *(const f32x4*)(p);
        f32x4 v1 = *(const f32x4*)(p + 4);
#pragma unroll
        for (int i = 0; i < 4; ++i) {
            o[i] = (short)f2bf(v0[i]);
            o[4 + i] = (short)f2bf(v1[i]);
        }
    } else {
#pragma unroll
        for (int i = 0; i < 8; ++i) {
            float f = (kb + i < FIN) ? p[i] : 0.f;
            o[i] = (short)f2bf(f);
        }
    }
    *(short8*)&xbf[(size_t)r * KP0 + c * 32 + ss * 8] = o;
}

// ---------------- merged weight transpose+convert, PRE-SWIZZLED, coalesced reads ----------------
#define W0E (512 * KP0)
#define W1E (512 * FH)
#define W2E (128 * FH)
__global__ void k_cvtw(const float* __restrict__ Ws0, const float* __restrict__ Wn0,
                       const float* __restrict__ Ws1, const float* __restrict__ Wn1,
                       const float* __restrict__ Ws2, const float* __restrict__ Wn2,
                       ushort* __restrict__ Wt0, ushort* __restrict__ Wt1,
                       ushort* __restrict__ Wt2) {
    int gid = blockIdx.x * blockDim.x + threadIdx.x;
    if (gid < W0E) {
        int kl = gid >> 9, n = gid & 511;
        int ks = (kl & ~31) | ((((kl >> 3) & 3) ^ ((n >> 1) & 3)) << 3) | (kl & 7);
        float v = 0.f;
        if (kl < FIN) v = (n < FH) ? Ws0[(size_t)kl * FH + n] : Wn0[(size_t)kl * FH + (n - FH)];
        Wt0[(size_t)n * KP0 + ks] = f2bf(v);
    } else if (gid < W0E + W1E) {
        int gg = gid - W0E;
        int k = gg >> 9, n = gg & 511;
        int ks = (k & ~31) | ((((k >> 3) & 3) ^ ((n >> 1) & 3)) << 3) | (k & 7);
        float v = (n < FH) ? Ws1[(size_t)k * FH + n] : Wn1[(size_t)k * FH + (n - FH)];
        Wt1[(size_t)n * FH + ks] = f2bf(v);
    } else if (gid < W0E + W1E + W2E) {
        int gg = gid - W0E - W1E;
        int k = gg >> 7, n = gg & 127;
        int ks = (k & ~31) | ((((k >> 3) & 3) ^ ((n >> 1) & 3)) << 3) | (k & 7);
        float v = 0.f;
        if (n < FC) v = Ws2[(size_t)k * FC + n];
        else if (n >= 64 && n < 64 + FC) v = Wn2[(size_t)k * FC + (n - 64)];
        Wt2[(size_t)n * FH + ks] = f2bf(v);
    }
}

// ================= 256x256 MFMA GEMM: gload_lds + 4-buffer 3-ahead, 1 barrier =================
#define TB2 8192    // ushorts per 256x32 tile buffer
#define NB2 4

__global__ __launch_bounds__(512, 2) void k_mm256(const ushort* __restrict__ A,
                                                  const ushort* __restrict__ Bt,
                                                  ushort* __restrict__ C,
                                                  const int M, const int lda,
                                                  const int Kpad, const int ldc,
                                                  const int nbx) {
    const int nwg = gridDim.x;
    const int bid = blockIdx.x;
    const int q = nwg >> 3, r = nwg & 7;
    const int xcd = bid & 7, ii = bid >> 3;
    const int swz = (xcd < r ? xcd * (q + 1) : r * (q + 1) + (xcd - r) * q) + ii;
    const int bm = (swz / nbx) * 256;
    const int bn = (swz % nbx) * 256;

    __shared__ ushort As[NB2 * TB2];   // 64 KB
    __shared__ ushort Bs[NB2 * TB2];   // 64 KB

    const int t = threadIdx.x;
    const int wid = t >> 6, lane = t & 63;
    const int wr = (wid >> 2) * 128, wc = (wid & 3) * 64;
    const int lr = lane & 15, g = lane >> 4;

    f32x4 acc[8][4] = {};

    const ushort* asrc[2]; const ushort* bsrc[2]; int cdst[2];
#pragma unroll
    for (int j = 0; j < 2; ++j) {
        const int c = j * 8 + wid;
        const int row = c * 16 + (lane >> 2);
        const int arow = min(bm + row, M - 1);
        asrc[j] = A + (size_t)arow * lda + ((lane & 3) << 3);
        bsrc[j] = Bt + (size_t)(bn + row) * Kpad + ((lane & 3) << 3);
        cdst[j] = c * 512;
    }

    int roA[8], roB[4];
#pragma unroll
    for (int m = 0; m < 8; ++m) {
        const int row = wr + m * 16 + lr;
        roA[m] = row * 32 + ((g ^ ((row >> 1) & 3)) << 3);
    }
#pragma unroll
    for (int n = 0; n < 4; ++n) {
        const int col = wc + n * 16 + lr;
        roB[n] = col * 32 + ((g ^ ((col >> 1) & 3)) << 3);
    }

    auto stage = [&](int tile) {
        const int k0 = tile * 32;
        const int ho = (tile & (NB2 - 1)) * TB2;
        g2l16(asrc[0] + k0, &As[ho + cdst[0]]);
        g2l16(asrc[1] + k0, &As[ho + cdst[1]]);
        g2l16(bsrc[0] + k0, &Bs[ho + cdst[0]]);
        g2l16(bsrc[1] + k0, &Bs[ho + cdst[1]]);
    };

    const int nt = Kpad / 32;
#pragma unroll
    for (int p = 0; p < 3; ++p) if (p < nt) stage(p);

    for (int it = 0; it < nt; ++it) {
        const int rmn = nt - 1 - it;
        if (rmn >= 2)      asm volatile("s_waitcnt vmcnt(8)" ::: "memory");
        else if (rmn == 1) asm volatile("s_waitcnt vmcnt(4)" ::: "memory");
        else               asm volatile("s_waitcnt vmcnt(0)" ::: "memory");
        __builtin_amdgcn_s_barrier();           // all waves: tile `it` resident
        __builtin_amdgcn_sched_barrier(0);      // pin ds_reads below the barrier

        if (it + 3 < nt) stage(it + 3);         // buf freed at it-1

        const ushort* Ab = &As[(it & (NB2 - 1)) * TB2];
        const ushort* Bb = &Bs[(it & (NB2 - 1)) * TB2];
        short8 af[8], bfr[4];
#pragma unroll
        for (int m = 0; m < 8; ++m) af[m] = *(const short8*)&Ab[roA[m]];
#pragma unroll
        for (int n = 0; n < 4; ++n) bfr[n] = *(const short8*)&Bb[roB[n]];
#pragma unroll
        for (int m = 0; m < 8; ++m)
#pragma unroll
            for (int n = 0; n < 4; ++n)
                acc[m][n] = __builtin_amdgcn_mfma_f32_16x16x32_bf16(af[m], bfr[n], acc[m][n], 0, 0, 0);
    }

#pragma unroll
    for (int m = 0; m < 8; ++m) {
#pragma unroll
        for (int i = 0; i < 4; ++i) {
            const int row = bm + wr + m * 16 + g * 4 + i;
            if (row >= M) continue;
#pragma unroll
            for (int n = 0; n < 4; ++n) {
                const int col = bn + wc + n * 16 + lr;
                C[(size_t)row * ldc + col] = f2bf(acc[m][n][i]);
            }
        }
    }
}

// ================= 128x128 MFMA GEMM — used for L2 (N=128) =================
#define BMT 128
#define TBUF 4096
#define NBUF 5

__global__ __launch_bounds__(256, 4) void k_mm(const ushort* __restrict__ A,
                                               const ushort* __restrict__ Bt,
                                               ushort* __restrict__ C,
                                               const int M, const int lda,
                                               const int Kpad, const int ldc,
                                               const int nbx) {
    const int nwg = gridDim.x;
    const int bid = blockIdx.x;
    const int q = nwg >> 3, r = nwg & 7;
    const int xcd = bid & 7, ii = bid >> 3;
    const int swz = (xcd < r ? xcd * (q + 1) : r * (q + 1) + (xcd - r) * q) + ii;
    const int bm = (swz / nbx) * BMT;
    const int bn = (swz % nbx) * BMT;

    __shared__ ushort As[NBUF * TBUF];
    __shared__ ushort Bs[NBUF * TBUF];

    const int t = threadIdx.x;
    const int wid = t >> 6, lane = t & 63;
    const int wr = (wid >> 1) * 64, wc = (wid & 1) * 64;
    const int lr = lane & 15, g = lane >> 4;

    f32x4 acc[4][4] = {};

    const ushort* asrc[2]; const ushort* bsrc[2]; int cdst[2];
#pragma unroll
    for (int j = 0; j < 2; ++j) {
        const int c = j * 4 + wid;
        const int row = c * 16 + (lane >> 2);
        const int arow = min(bm + row, M - 1);
        asrc[j] = A + (size_t)arow * lda + ((lane & 3) << 3);
        bsrc[j] = Bt + (size_t)(bn + row) * Kpad + ((lane & 3) << 3);
        cdst[j] = c * 512;
    }

    int roA[4], roB[4];
#pragma unroll
    for (int m = 0; m < 4; ++m) {
        const int row = wr + m * 16 + lr;
        roA[m] = row * 32 + ((g ^ ((row >> 1) & 3)) << 3);
    }
#pragma unroll
    for (int n = 0; n < 4; ++n) {
        const int col = wc + n * 16 + lr;
        roB[n] = col * 32 + ((g ^ ((col >> 1) & 3)) << 3);
    }

    auto stage = [&](int tile) {
        const int k0 = tile * 32;
        const int ho = (tile % NBUF) * TBUF;
        g2l16(asrc[0] + k0, &As[ho + cdst[0]]);
        g2l16(asrc[1] + k0, &As[ho + cdst[1]]);
        g2l16(bsrc[0] + k0, &Bs[ho + cdst[0]]);
        g2l16(bsrc[1] + k0, &Bs[ho + cdst[1]]);
    };

    const int nt = Kpad / 32;
#pragma unroll
    for (int p = 0; p < 4; ++p) if (p < nt) stage(p);

    for (int it = 0; it < nt; ++it) {
        const int rmn = nt - 1 - it;
        if (rmn >= 3)      asm volatile("s_waitcnt vmcnt(12)" ::: "memory");
        else if (rmn == 2) asm volatile("s_waitcnt vmcnt(8)"  ::: "memory");
        else if (rmn == 1) asm volatile("s_waitcnt vmcnt(4)"  ::: "memory");
        else               asm volatile("s_waitcnt vmcnt(0)"  ::: "memory");
        __builtin_amdgcn_s_barrier();
        __builtin_amdgcn_sched_barrier(0);

        if (it + 4 < nt) stage(it + 4);

        const ushort* Ab = &As[(it % NBUF) * TBUF];
        const ushort* Bb = &Bs[(it % NBUF) * TBUF];
        short8 af[4], bfr[4];
#pragma unroll
        for (int m = 0; m < 4; ++m) af[m] = *(const short8*)&Ab[roA[m]];
#pragma unroll
        for (int n = 0; n < 4; ++n) bfr[n] = *(const short8*)&Bb[roB[n]];
#pragma unroll
        for (int m = 0; m < 4; ++m)
#pragma unroll
            for (int n = 0; n < 4; ++n)
                acc[m][n] = __builtin_amdgcn_mfma_f32_16x16x32_bf16(af[m], bfr[n], acc[m][n], 0, 0, 0);
    }

#pragma unroll
    for (int m = 0; m < 4; ++m) {
#pragma unroll
        for (int i = 0; i < 4; ++i) {
            const int row = bm + wr + m * 16 + g * 4 + i;
            if (row >= M) continue;
#pragma unroll
            for (int n = 0; n < 4; ++n) {
                const int col = bn + wc + n * 16 + lr;
                C[(size_t)row * ldc + col] = f2bf(acc[m][n][i]);
            }
        }
    }
}

// ---------------- fused gather-aggregate + combine, F=256, unroll-4 ----------------
// latency-bound on random row gathers: 4 independent loads in flight per lane.
__global__ void k_gac256(const ushort* __restrict__ C, const int* __restrict__ rowptr,
                         const int* __restrict__ eidx, const float* __restrict__ bias,
                         ushort* __restrict__ hout) {
    int gid = blockIdx.x * blockDim.x + threadIdx.x;
    int node = gid >> 6;
    if (node >= NODES) return;
    const int l4 = (gid & 63) << 2;
    const int beg = rowptr[node];
    const int end = rowptr[node + 1];
    float a0 = 0.f, a1 = 0.f, a2 = 0.f, a3 = 0.f;
    int e = beg;
    for (; e + 3 < end; e += 4) {
        const int s0 = eidx[e], s1 = eidx[e + 1], s2 = eidx[e + 2], s3 = eidx[e + 3];
        const ushort4 v0 = *(const ushort4*)&C[(size_t)s0 * 512 + 256 + l4];
        const ushort4 v1 = *(const ushort4*)&C[(size_t)s1 * 512 + 256 + l4];
        const ushort4 v2 = *(const ushort4*)&C[(size_t)s2 * 512 + 256 + l4];
        const ushort4 v3 = *(const ushort4*)&C[(size_t)s3 * 512 + 256 + l4];
        a0 += (bf2f(v0.x) + bf2f(v1.x)) + (bf2f(v2.x) + bf2f(v3.x));
        a1 += (bf2f(v0.y) + bf2f(v1.y)) + (bf2f(v2.y) + bf2f(v3.y));
        a2 += (bf2f(v0.z) + bf2f(v1.z)) + (bf2f(v2.z) + bf2f(v3.z));
        a3 += (bf2f(v0.w) + bf2f(v1.w)) + (bf2f(v2.w) + bf2f(v3.w));
    }
    for (; e < end; ++e) {
        const int s = eidx[e];
        const ushort4 v = *(const ushort4*)&C[(size_t)s * 512 + 256 + l4];
        a0 += bf2f(v.x); a1 += bf2f(v.y); a2 += bf2f(v.z); a3 += bf2f(v.w);
    }
    const float inv = 1.f / (float)max(end - beg, 1);
    const ushort4 hs = *(const ushort4*)&C[(size_t)node * 512 + l4];
    const f32x4 bv = *(const f32x4*)&bias[l4];
    ushort4 w;
    w.x = f2bf(fmaxf(bf2f(hs.x) + a0 * inv + bv[0], 0.f));
    w.y = f2bf(fmaxf(bf2f(hs.y) + a1 * inv + bv[1], 0.f));
    w.z = f2bf(fmaxf(bf2f(hs.z) + a2 * inv + bv[2], 0.f));
    w.w = f2bf(fmaxf(bf2f(hs.w) + a3 * inv + bv[3], 0.f));
    const int scol = (l4 & ~31) + ((((l4 >> 3) & 3) ^ ((node >> 1) & 3)) << 3) + (l4 & 7);
    *(ushort4*)&hout[(size_t)node * 256 + scol] = w;
}

// ---------------- final layer gather, F=47, u32 loads (2 cols/lane), unroll-4 ----------------
// C2 row = 128 bf16 = 64 u32. Lane l (0..23) covers cols {2l, 2l+1}; cols 47
// and 111 are the zero-pad region of Wt2 (harmless). Halves load count vs
// scalar-2B and keeps 4 gathers in flight.
__global__ void k_gac47(const ushort* __restrict__ C, const int* __restrict__ rowptr,
                        const int* __restrict__ eidx, const float* __restrict__ bias,
                        float* __restrict__ out) {
    int gid = blockIdx.x * blockDim.x + threadIdx.x;
    int node = gid >> 6;
    if (node >= NODES) return;
    const int l = gid & 63;
    if (l >= 24) return;
    const uint32_t* C32 = (const uint32_t*)C;   // row stride 64 u32
    const int beg = rowptr[node];
    const int end = rowptr[node + 1];
    float a0 = 0.f, a1 = 0.f;
    int e = beg;
    for (; e + 3 < end; e += 4) {
        const uint32_t u0 = C32[(size_t)eidx[e]     * 64 + 32 + l];
        const uint32_t u1 = C32[(size_t)eidx[e + 1] * 64 + 32 + l];
        const uint32_t u2 = C32[(size_t)eidx[e + 2] * 64 + 32 + l];
        const uint32_t u3 = C32[(size_t)eidx[e + 3] * 64 + 32 + l];
        a0 += (bf2f((ushort)u0) + bf2f((ushort)u1)) + (bf2f((ushort)u2) + bf2f((ushort)u3));
        a1 += (bf2f((ushort)(u0 >> 16)) + bf2f((ushort)(u1 >> 16)))
            + (bf2f((ushort)(u2 >> 16)) + bf2f((ushort)(u3 >> 16)));
    }
    for (; e < end; ++e) {
        const uint32_t u = C32[(size_t)eidx[e] * 64 + 32 + l];
        a0 += bf2f((ushort)u);
        a1 += bf2f((ushort)(u >> 16));
    }
    const float inv = 1.f / (float)max(end - beg, 1);
    const uint32_t us = C32[(size_t)node * 64 + l];   // self cols 2l, 2l+1
    const int c0 = 2 * l, c1 = 2 * l + 1;
    out[(size_t)node * FC + c0] = bf2f((ushort)us) + a0 * inv + bias[c0];
    if (c1 < FC)
        out[(size_t)node * FC + c1] = bf2f((ushort)(us >> 16)) + a1 * inv + bias[c1];
}

extern "C" void kernel_launch(void* const* d_in, const int* in_sizes, int n_in,
                              void* d_out, int out_size, void* d_ws, size_t ws_size,
                              hipStream_t stream) {
    const float* x       = (const float*)d_in[0];
    const int*   src     = (const int*)d_in[1];
    const int*   dst     = (const int*)d_in[2];
    const float* Wself0  = (const float*)d_in[3];
    const float* Wneigh0 = (const float*)d_in[4];
    const float* b0      = (const float*)d_in[5];
    const float* Wself1  = (const float*)d_in[6];
    const float* Wneigh1 = (const float*)d_in[7];
    const float* b1      = (const float*)d_in[8];
    const float* Wself2  = (const float*)d_in[9];
    const float* Wneigh2 = (const float*)d_in[10];
    const float* b2      = (const float*)d_in[11];
    float* out = (float*)d_out;

    char* w = (char*)d_ws;
    ushort* Cbuf = (ushort*)w;   w += (size_t)NODES * 512 * 2;   // 51.2 MB
    ushort* xbf  = (ushort*)w;   w += (size_t)NODES * KP0 * 2;   // 99.2 MB
    ushort* hbuf = xbf;          // aliases xbf: xbf dead once L0 GEMM completes
    ushort* Wt0  = (ushort*)w;   w += (size_t)W0E * 2;
    ushort* Wt1  = (ushort*)w;   w += (size_t)W1E * 2;
    ushort* Wt2  = (ushort*)w;   w += (size_t)W2E * 2;
    int* rowptr  = (int*)w;      w += (NODES + 1) * sizeof(int);
    int* cursor  = (int*)w;      w += NODES * sizeof(int);
    int* eidx    = (int*)w;

    dim3 blk(256);

    // ---- CSR build ----
    hipMemsetAsync(cursor, 0, NODES * sizeof(int), stream);
    k_deg_count<<<(EDGES + 255) / 256, blk, 0, stream>>>(dst, cursor, EDGES);
    k_scan<<<1, 1024, 0, stream>>>(cursor, rowptr, cursor, NODES);
    k_fill<<<(EDGES + 255) / 256, blk, 0, stream>>>(src, dst, cursor, eidx, EDGES);

    // ---- conversions (pre-swizzled) ----
    k_cvtw<<<(W0E + W1E + W2E + 255) / 256, blk, 0, stream>>>(
        Wself0, Wneigh0, Wself1, Wneigh1, Wself2, Wneigh2, Wt0, Wt1, Wt2);
    k_cvtx<<<(NODES * (KP0 / 8) + 255) / 256, blk, 0, stream>>>(x, xbf);

    const int gat_blocks = (int)(((size_t)NODES * 64 + 255) / 256);
    const int nbyM2 = (NODES + 255) / 256;      // 196 (256-row tiles)
    const int nbyM  = (NODES + BMT - 1) / BMT;  // 391 (128-row tiles)

    // ---- Layer 0: C0 = xbf @ [Wself0|Wneigh0]  (M=50000, N=512, K=992) ----
    k_mm256<<<dim3(2 * nbyM2), dim3(512), 0, stream>>>(xbf, Wt0, Cbuf, NODES, KP0, KP0, 512, 2);
    k_gac256<<<gat_blocks, blk, 0, stream>>>(Cbuf, rowptr, eidx, b0, hbuf);

    // ---- Layer 1: C1 = h1 @ [Wself1|Wneigh1]  (K=256) ----
    k_mm256<<<dim3(2 * nbyM2), dim3(512), 0, stream>>>(hbuf, Wt1, Cbuf, NODES, FH, FH, 512, 2);
    k_gac256<<<gat_blocks, blk, 0, stream>>>(Cbuf, rowptr, eidx, b1, hbuf);

    // ---- Layer 2: C2 = h2 @ [Wself2|Wneigh2 padded]  (N=128, K=256) ----
    k_mm<<<dim3(nbyM), blk, 0, stream>>>(hbuf, Wt2, Cbuf, NODES, FH, FH, 128, 1);
    k_gac47<<<gat_blocks, blk, 0, stream>>>(Cbuf, rowptr, eidx, b2, out);
}